// Round 3
// baseline (737.126 us; speedup 1.0000x reference)
//
#include <hip/hip_runtime.h>
#include <hip/hip_fp16.h>

#define TT 512
#define BB 128
#define EE 128
#define HH 128

typedef _Float16 half2_t __attribute__((ext_vector_type(2)));
typedef _Float16 half8_t __attribute__((ext_vector_type(8)));
typedef float    float4_t __attribute__((ext_vector_type(4)));

__device__ __forceinline__ half2_t as_h2(unsigned int u) {
    return __builtin_bit_cast(half2_t, u);
}
__device__ __forceinline__ half2_t pack2(float x, float y) {
    half2_t r; r.x = (_Float16)x; r.y = (_Float16)y; return r;
}
__device__ __forceinline__ float fdot2(half2_t a, half2_t b, float c) {
#if __has_builtin(__builtin_amdgcn_fdot2)
    return __builtin_amdgcn_fdot2(a, b, c, false);
#else
    return c + (float)a.x * (float)b.x + (float)a.y * (float)b.y;
#endif
}
__device__ __forceinline__ float sigmoidf_fast(float x) {
    return 1.0f / (1.0f + __expf(-x));
}
__device__ __forceinline__ float tanhf_fast(float x) {
    return 2.0f / (1.0f + __expf(-2.0f * x)) - 1.0f;
}

// ---- kernel 0: convert Wih_f / Wih_b (f32) -> W16 (f16), layout [dir][512][128]
__global__ __launch_bounds__(256) void wconv_kernel(
    const float* __restrict__ Wf, const float* __restrict__ Wb,
    _Float16* __restrict__ W16)
{
    int i = blockIdx.x * 256 + threadIdx.x;   // 0 .. 131071
    float v = (i < 65536) ? Wf[i] : Wb[i - 65536];
    W16[i] = (_Float16)v;
}

// ---- kernel 1: xp[dir][m][g] = sum_k emb[x[m]][k] * Wih_dir[g][k]   (f16 out)
// MFMA 16x16x32 f16. Block: 256 thr / 4 waves; tile M=64 x N=512 (one dir).
// Verified fragment layouts (m89/m91): A: m=lane&15, k=(lane>>4)*8+j;
// B: n=lane&15, k=(lane>>4)*8+j; D: col(n)=lane&15, row(m)=(lane>>4)*4+reg.
__global__ __launch_bounds__(256) void xp_gemm_kernel(
    const int* __restrict__ x, const float* __restrict__ emb,
    const _Float16* __restrict__ W16, _Float16* __restrict__ xp)
{
    const int tid = threadIdx.x;
    const int m0  = blockIdx.x * 64;
    const int dir = blockIdx.y;

    __shared__ _Float16 A[64 * 136];   // 64 rows x 128 halfs, pad 8 halfs

    {   // stage gathered emb rows -> f16 LDS. 4 threads per row.
        int r = tid >> 2, q = tid & 3;
        int id = x[m0 + r];
        const float4* src = (const float4*)(emb + (size_t)id * EE + 32 * q);
        half2_t* dst = (half2_t*)(A + r * 136 + 32 * q);
        #pragma unroll
        for (int i = 0; i < 8; ++i) {
            float4 v = src[i];
            dst[2 * i]     = pack2(v.x, v.y);
            dst[2 * i + 1] = pack2(v.z, v.w);
        }
    }
    __syncthreads();

    const int wave = tid >> 6, lane = tid & 63;
    const int lm = lane & 15, lq = lane >> 4;

    half8_t af[4];
    #pragma unroll
    for (int kk = 0; kk < 4; ++kk)
        af[kk] = *(const half8_t*)(A + lm * 136 + kk * 32 + lq * 8);

    const _Float16* wbase = W16 + (size_t)dir * 512 * 128;
    _Float16* xpd = xp + ((size_t)dir * 65536 + (size_t)m0) * 512;

    #pragma unroll
    for (int nt = 0; nt < 8; ++nt) {
        int n0 = wave * 128 + nt * 16;
        float4_t acc = {0.f, 0.f, 0.f, 0.f};
        #pragma unroll
        for (int kk = 0; kk < 4; ++kk) {
            half8_t bf = *(const half8_t*)(wbase + (size_t)(n0 + lm) * 128 + kk * 32 + lq * 8);
            acc = __builtin_amdgcn_mfma_f32_16x16x32_f16(af[kk], bf, acc, 0, 0, 0);
        }
        #pragma unroll
        for (int r = 0; r < 4; ++r) {
            int row = lq * 4 + r;
            xpd[(size_t)row * 512 + n0 + lm] = (_Float16)acc[r];
        }
    }
}

// ---- kernel 2: recurrence. One block per (dir, b), 512 threads.
// thread = (grp = tid>>2 in [0,128), ks = tid&3). 4 passes p: gate g = 128p+grp,
// K-slice [32ks, 32ks+32). Per step: 64 B LDS h-read/thread (vs 512 B before),
// 16 fdot2/pass, 2 shfl_xor reduce, pass-uniform activation, lane ks==0 writes.
__global__ __launch_bounds__(512, 1) void bilstm_rec_kernel(
    const _Float16* __restrict__ xp,
    const float* __restrict__ Whh_f, const float* __restrict__ Whh_b,
    const float* __restrict__ bih_f, const float* __restrict__ bhh_f,
    const float* __restrict__ bih_b, const float* __restrict__ bhh_b,
    float* __restrict__ pooled)
{
    const int tid = threadIdx.x;
    const int b   = blockIdx.x & (BB - 1);
    const int dir = blockIdx.x >> 7;

    const float* Whh = dir ? Whh_b : Whh_f;
    const float* bih = dir ? bih_b : bih_f;
    const float* bhh = dir ? bhh_b : bhh_f;

    const int grp = tid >> 2;
    const int ks  = tid & 3;

    __shared__ __align__(16) _Float16 h_sm[HH];
    __shared__ float gates_sm[4 * HH];

    // weight slices: wh[p][i] = Whh[128p+grp][32ks+2i .. +2] as f16x2 (64 VGPRs)
    half2_t wh[4][16];
    float bias[4];
    #pragma unroll
    for (int p = 0; p < 4; ++p) {
        int g = p * 128 + grp;
        const float4* src = (const float4*)(Whh + (size_t)g * HH + 32 * ks);
        #pragma unroll
        for (int i = 0; i < 8; ++i) {
            float4 v = src[i];
            wh[p][2 * i]     = pack2(v.x, v.y);
            wh[p][2 * i + 1] = pack2(v.z, v.w);
        }
        bias[p] = bih[g] + bhh[g];
    }

    if (tid < HH) h_sm[tid] = (_Float16)0.0f;

    const _Float16* xpb = xp + ((size_t)dir * 65536 + (size_t)b * TT) * 512;

    float xpc[4];
    {
        int t0 = dir ? (TT - 1) : 0;
        #pragma unroll
        for (int p = 0; p < 4; ++p)
            xpc[p] = (float)xpb[(size_t)t0 * 512 + p * 128 + grp];
    }
    __syncthreads();

    float c = 0.0f, hmax = -1e30f;

    for (int t = 0; t < TT; ++t) {
        // prefetch next step's xp (hidden under the dot passes)
        float xpn[4];
        {
            int tn = (t + 1 < TT) ? (t + 1) : t;
            int ta = dir ? (TT - 1 - tn) : tn;
            #pragma unroll
            for (int p = 0; p < 4; ++p)
                xpn[p] = (float)xpb[(size_t)ta * 512 + p * 128 + grp];
        }

        // h K-slice: 64 B (2-way bank aliasing only)
        const uint4* hv4 = (const uint4*)(h_sm + 32 * ks);
        uint4 hA = hv4[0], hB = hv4[1], hC = hv4[2], hD = hv4[3];
        half2_t hh[16] = {as_h2(hA.x), as_h2(hA.y), as_h2(hA.z), as_h2(hA.w),
                          as_h2(hB.x), as_h2(hB.y), as_h2(hB.z), as_h2(hB.w),
                          as_h2(hC.x), as_h2(hC.y), as_h2(hC.z), as_h2(hC.w),
                          as_h2(hD.x), as_h2(hD.y), as_h2(hD.z), as_h2(hD.w)};

        #pragma unroll
        for (int p = 0; p < 4; ++p) {
            float a0 = 0.f, a1 = 0.f, a2 = 0.f, a3 = 0.f;
            #pragma unroll
            for (int i = 0; i < 4; ++i) {
                a0 = fdot2(hh[4 * i + 0], wh[p][4 * i + 0], a0);
                a1 = fdot2(hh[4 * i + 1], wh[p][4 * i + 1], a1);
                a2 = fdot2(hh[4 * i + 2], wh[p][4 * i + 2], a2);
                a3 = fdot2(hh[4 * i + 3], wh[p][4 * i + 3], a3);
            }
            float s = (a0 + a1) + (a2 + a3);
            s += __shfl_xor(s, 1);
            s += __shfl_xor(s, 2);
            float pre = s + bias[p] + xpc[p];
            float act = (p == 2) ? tanhf_fast(pre) : sigmoidf_fast(pre);
            if (ks == 0) gates_sm[p * 128 + grp] = act;
        }
        __syncthreads();

        if (tid < HH) {
            float ig = gates_sm[tid];
            float fg = gates_sm[HH + tid];
            float gg = gates_sm[2 * HH + tid];
            float og = gates_sm[3 * HH + tid];
            c = fg * c + ig * gg;
            float hval = og * tanhf_fast(c);
            hmax = fmaxf(hmax, hval);
            h_sm[tid] = (_Float16)hval;
        }
        #pragma unroll
        for (int p = 0; p < 4; ++p) xpc[p] = xpn[p];
        __syncthreads();
    }

    if (tid < HH)
        pooled[(size_t)b * 256 + dir * HH + tid] = hmax;
}

// ---- kernel 3: pooled (128,256) -> relu(W1·+b1) -> sigmoid(W2·+b2) -> (128,1)
__global__ __launch_bounds__(64) void mlp_kernel(
    const float* __restrict__ pooled, const float* __restrict__ W1,
    const float* __restrict__ b1, const float* __restrict__ W2,
    const float* __restrict__ b2, float* __restrict__ out)
{
    const int b = blockIdx.x;
    const int j = threadIdx.x;
    const float4* p = (const float4*)(pooled + (size_t)b * 256);
    const float4* w = (const float4*)(W1 + (size_t)j * 256);
    float s = 0.0f;
    #pragma unroll
    for (int q = 0; q < 64; ++q) {
        float4 pv = p[q];
        float4 wv = w[q];
        s += pv.x * wv.x + pv.y * wv.y + pv.z * wv.z + pv.w * wv.w;
    }
    s += b1[j];
    s = fmaxf(s, 0.0f);
    float v = W2[j] * s;
    #pragma unroll
    for (int off = 32; off; off >>= 1) v += __shfl_down(v, off);
    if (j == 0) out[b] = 1.0f / (1.0f + __expf(-(v + b2[0])));
}

extern "C" void kernel_launch(void* const* d_in, const int* in_sizes, int n_in,
                              void* d_out, int out_size, void* d_ws, size_t ws_size,
                              hipStream_t stream) {
    const int*   x     = (const int*)d_in[0];
    const float* emb   = (const float*)d_in[1];
    const float* Wih_f = (const float*)d_in[2];
    const float* Whh_f = (const float*)d_in[3];
    const float* bih_f = (const float*)d_in[4];
    const float* bhh_f = (const float*)d_in[5];
    const float* Wih_b = (const float*)d_in[6];
    const float* Whh_b = (const float*)d_in[7];
    const float* bih_b = (const float*)d_in[8];
    const float* bhh_b = (const float*)d_in[9];
    const float* W1    = (const float*)d_in[10];
    const float* b1    = (const float*)d_in[11];
    const float* W2    = (const float*)d_in[12];
    const float* b2    = (const float*)d_in[13];
    float* out = (float*)d_out;

    // workspace layout
    char* ws = (char*)d_ws;
    float*     pooled = (float*)ws;                       // 128 KB
    _Float16*  W16    = (_Float16*)(ws + 131072);         // 256 KB
    _Float16*  xp     = (_Float16*)(ws + 393216);         // 128 MB: [2][65536][512] f16

    hipLaunchKernelGGL(wconv_kernel, dim3(512), dim3(256), 0, stream,
                       Wih_f, Wih_b, W16);
    hipLaunchKernelGGL(xp_gemm_kernel, dim3(1024, 2), dim3(256), 0, stream,
                       x, emb, W16, xp);
    hipLaunchKernelGGL(bilstm_rec_kernel, dim3(256), dim3(512), 0, stream,
                       xp, Whh_f, Whh_b, bih_f, bhh_f, bih_b, bhh_b, pooled);
    hipLaunchKernelGGL(mlp_kernel, dim3(128), dim3(64), 0, stream,
                       pooled, W1, b1, W2, b2, out);
}